// Round 5
// baseline (405.764 us; speedup 1.0000x reference)
//
#include <hip/hip_runtime.h>
#include <math.h>

#define NUM_TREES 20000
#define MAX_DEPTH 8
#define MAX_SIZE  40
#define VOCAB     30000
#define DIM       128
#define TOT       (MAX_DEPTH * MAX_SIZE)       // 320 tokens per tree
#define NGATE     ((MAX_DEPTH - 1) * MAX_SIZE) // 280 gated rows (depths 0..6)
#define NTILE     8
#define TILE_ROWS (VOCAB / NTILE)              // 3750 rows = 1.92 MB (L2-resident)
#define TPA       4                            // trees per block (wave per tree)
#define GD        8                            // gather MLP depth (rows in flight)

typedef unsigned long long ull;

__device__ __forceinline__ double waveSumD(double v) {
    v += __shfl_xor(v, 32);
    v += __shfl_xor(v, 16);
    v += __shfl_xor(v, 8);
    v += __shfl_xor(v, 4);
    v += __shfl_xor(v, 2);
    v += __shfl_xor(v, 1);
    return v;
}

// One packed butterfly for three independent fp64 sums (ILP hides the
// per-step shuffle latency across the three chains).
__device__ __forceinline__ void waveSum3(double& a, double& b, double& c) {
    #pragma unroll
    for (int m = 32; m >= 1; m >>= 1) {
        a += __shfl_xor(a, m);
        b += __shfl_xor(b, m);
        c += __shfl_xor(c, m);
    }
}

// masks may arrive as 1-byte bool or int32; probe word 0 (all-ones input:
// byte layout reads 0x01010101, int32 layout reads 0x00000001).
__device__ __forceinline__ int loadMask(const void* m, size_t idx, bool asByte) {
    return asByte ? (int)((const unsigned char*)m)[idx] : ((const int*)m)[idx];
}

// Phase 0: ts[v] = dot(embedding[v], context_weight) in fp64 (one wave per row)
__global__ __launch_bounds__(256) void tokscore_kernel(
        const float* __restrict__ emb, const float* __restrict__ cw,
        double* __restrict__ ts) {
    int row  = (blockIdx.x * blockDim.x + threadIdx.x) >> 6;
    int lane = threadIdx.x & 63;
    if (row >= VOCAB) return;
    float2 e2 = *(const float2*)(emb + (size_t)row * DIM + lane * 2);
    float2 w2 = *(const float2*)(cw + lane * 2);
    double p = (double)e2.x * (double)w2.x + (double)e2.y * (double)w2.y;
    p = waveSumD(p);
    if (lane == 0) ts[row] = p;
}

// Phase A: wave-per-tree fp64 recursion, register-only. Bucketing by vocab
// tile via ballot/popcount sweeps (no LDS, no atomics, no barriers).
// Emits packed pairs: coef-f32-bits in high 32, token in low 32.
__global__ __launch_bounds__(256, 4) void phaseA_kernel(
        const int* __restrict__ tokens, const void* __restrict__ masks,
        const double* __restrict__ ts,
        ull* __restrict__ pairs, int* __restrict__ toff) {
    const int tid  = threadIdx.x;
    const int w    = tid >> 6;          // wave id = local tree index
    const int s    = tid & 63;          // lane = sibling position
    const int tree = blockIdx.x * TPA + w;
    const size_t base = (size_t)tree * TOT;
    const bool mByte = (((const int*)masks)[0] != 1);   // see loadMask comment
    const bool inS = s < MAX_SIZE;

    // ---- per-wave load: tokens/masks/scores into registers.
    int    tok[MAX_DEPTH];
    double e[MAX_DEPTH];
    unsigned int valbit = 0, mskbit = 0;
    #pragma unroll
    for (int d = 0; d < MAX_DEPTH; ++d) {
        int t = -1, m = 0;
        if (inS) {
            t = tokens[base + d * MAX_SIZE + s];
            m = loadMask(masks, base + d * MAX_SIZE + s, mByte);
        }
        tok[d] = t < 0 ? 0 : t;
        e[d]   = inS ? ts[tok[d]] : 0.0;
        if (inS && m != 0) mskbit |= 1u << d;
        if (inS && m != 0 && t >= 0) valbit |= 1u << d;
    }
    unsigned int childbit = 0;
    #pragma unroll
    for (int d = 0; d < MAX_DEPTH - 1; ++d) {
        ull bal = __ballot((mskbit >> (d + 1)) & 1u);
        int nc = (int)__popcll(bal);
        if (nc < 1) nc = 1;
        if (((valbit >> d) & 1u) && s < nc) childbit |= 1u << d;
    }

    // ---- recursion (math identical to validated version; exp via HW f32
    // exp: rel err ~1e-7, cancels in the softmax ratio).
    double v7 = ((valbit >> 7) & 1u) ? 1.0 : 0.0;
    double pw = waveSumD(e[7] * v7);

    float  attnf[MAX_DEPTH - 1];
    double cArr[MAX_DEPTH - 1];
    #pragma unroll
    for (int d = MAX_DEPTH - 2; d >= 0; --d) {
        float  gf = 1.0f / (1.0f + __expf((float)(-e[d])));
        double cf = ((childbit >> d) & 1u) ? (double)gf : 0.0;  // gate*child
        double a  = fma(cf, pw, e[d]);
        double ex = ((valbit >> d) & 1u) ? (double)__expf((float)a) : 0.0;
        double s0 = ex;            // -> den
        double s1 = ex * cf;       // -> c * den
        double s2 = ex * e[d];     // -> (sum attn*e) * den
        waveSum3(s0, s1, s2);
        double inv = 1.0 / s0;
        double c   = s1 * inv;
        pw = fma(c, pw, s2 * inv);
        attnf[d] = (float)(ex * inv);   // attn
        cArr[d]  = c;
    }
    float coef[MAX_DEPTH];
    double prefix = 1.0;
    #pragma unroll
    for (int d = 0; d <= MAX_DEPTH - 2; ++d) {
        coef[d] = (float)(prefix * (double)attnf[d]);
        prefix *= cArr[d];
    }
    coef[MAX_DEPTH - 1] = (float)(prefix * v7);

    // ---- ballot-based tile bucketing (all indices compile-time after
    // unroll -> stays in registers; see rule about dynamic indexing).
    int tl[MAX_DEPTH];
    unsigned int nzbit = 0;
    #pragma unroll
    for (int d = 0; d < MAX_DEPTH; ++d) {
        tl[d] = tok[d] / TILE_ROWS;
        if (coef[d] != 0.0f) nzbit |= 1u << d;
    }
    const ull ltm = (1ull << s) - 1ull;    // lanes below me

    int cnt[NTILE];
    #pragma unroll
    for (int t = 0; t < NTILE; ++t) cnt[t] = 0;
    #pragma unroll
    for (int d = 0; d < MAX_DEPTH; ++d) {
        bool nz = (nzbit >> d) & 1u;
        #pragma unroll
        for (int t = 0; t < NTILE; ++t)
            cnt[t] += (int)__popcll(__ballot(nz && tl[d] == t));
    }
    int hoff[NTILE + 1];
    hoff[0] = 0;
    #pragma unroll
    for (int t = 0; t < NTILE; ++t) hoff[t + 1] = hoff[t] + cnt[t];

    int ridx[NTILE];
    #pragma unroll
    for (int t = 0; t < NTILE; ++t) ridx[t] = hoff[t];
    #pragma unroll
    for (int d = 0; d < MAX_DEPTH; ++d) {
        bool nz = (nzbit >> d) & 1u;
        int slot = -1;
        #pragma unroll
        for (int t = 0; t < NTILE; ++t) {
            ull m = __ballot(nz && tl[d] == t);
            if (nz && tl[d] == t) slot = ridx[t] + (int)__popcll(m & ltm);
            ridx[t] += (int)__popcll(m);
        }
        if (slot >= 0)
            pairs[base + slot] =
                ((ull)__float_as_uint(coef[d]) << 32) | (ull)(unsigned)tok[d];
    }
    // toff write: select hoff[s] without dynamic indexing (cndmask chain).
    int hv = 0;
    #pragma unroll
    for (int t = 1; t <= NTILE; ++t) hv = (s == t) ? hoff[t] : hv;
    if (s <= NTILE) toff[tree * (NTILE + 1) + s] = (int)base + hv;
}

// Phase B: per-tile gather, wave-per-tree, fp32, no LDS. Pair list is read
// via wave-uniform (scalar-path) loads; each row is one coalesced 512B read
// (64 lanes x float2). out itself is the fp32 accumulator across passes:
// tile 0 initializes, tiles 1..7 RMW (out stays L2-resident at 10.2 MB).
__global__ __launch_bounds__(256, 6) void gather_tile_kernel(
        const ull* __restrict__ pairs, const int* __restrict__ toff,
        const float* __restrict__ emb, float* __restrict__ out, int tile) {
    const int tid  = threadIdx.x;
    const int w    = tid >> 6;
    const int lane = tid & 63;
    const int tree = blockIdx.x * TPA + w;

    int beg = __builtin_amdgcn_readfirstlane(toff[tree * (NTILE + 1) + tile]);
    int end = __builtin_amdgcn_readfirstlane(toff[tree * (NTILE + 1) + tile + 1]);

    const float* ebase = emb + lane * 2;
    float a0 = 0.0f, a1 = 0.0f;
    int j = beg;
    for (; j + GD <= end; j += GD) {
        ull pr[GD]; float2 v[GD]; float wt[GD];
        #pragma unroll
        for (int k = 0; k < GD; ++k) pr[k] = pairs[j + k];
        #pragma unroll
        for (int k = 0; k < GD; ++k) {
            int tk = (int)(unsigned)pr[k];
            wt[k]  = __uint_as_float((unsigned)(pr[k] >> 32));
            v[k]   = *(const float2*)(ebase + (size_t)tk * DIM);
        }
        #pragma unroll
        for (int k = 0; k < GD; ++k) {
            a0 = fmaf(wt[k], v[k].x, a0);
            a1 = fmaf(wt[k], v[k].y, a1);
        }
    }
    for (; j < end; ++j) {
        ull pr = pairs[j];
        int tk = (int)(unsigned)pr;
        float wv = __uint_as_float((unsigned)(pr >> 32));
        float2 v = *(const float2*)(ebase + (size_t)tk * DIM);
        a0 = fmaf(wv, v.x, a0);
        a1 = fmaf(wv, v.y, a1);
    }

    float* op = out + (size_t)tree * DIM + lane * 2;
    if (tile == 0) {
        *(float2*)op = make_float2(a0, a1);
    } else {
        float2 p = *(const float2*)op;
        *(float2*)op = make_float2(p.x + a0, p.y + a1);
    }
}

// ---- Fallback single-kernel path (validated round 1) for small workspaces.
__global__ __launch_bounds__(256, 8) void encode_kernel(
        const int* __restrict__ tokens, const void* __restrict__ masks,
        const float* __restrict__ emb, const double* __restrict__ ts,
        float* __restrict__ out) {
    __shared__ int           s_tok[TOT];
    __shared__ double        s_e[TOT];
    __shared__ double        s_gc[NGATE];
    __shared__ unsigned char s_val[TOT];
    __shared__ unsigned char s_msk[TOT];
    __shared__ double        s_coef[TOT];
    __shared__ double        s_red[8][DIM];

    const int tree = blockIdx.x;
    const int tid  = threadIdx.x;
    const size_t base = (size_t)tree * TOT;
    const bool mByte = (((const int*)masks)[0] != 1);

    {
        const int iA = tid, iB = tid + 256;
        int tA = tokens[base + iA];
        int mA = loadMask(masks, base + iA, mByte);
        int tB = 0, mB = 0;
        if (iB < TOT) {
            tB = tokens[base + iB];
            mB = loadMask(masks, base + iB, mByte);
        }
        int tcA = tA < 0 ? 0 : tA;
        double eA = ts[tcA];
        s_tok[iA] = tcA;
        s_e[iA]   = eA;
        s_msk[iA] = (unsigned char)(mA != 0);
        s_val[iA] = (unsigned char)((mA != 0) && tA >= 0);
        if (iA < NGATE) s_gc[iA] = 1.0 / (1.0 + exp(-eA));
        if (iB < TOT) {
            int tcB = tB < 0 ? 0 : tB;
            double eB = ts[tcB];
            s_tok[iB] = tcB;
            s_e[iB]   = eB;
            s_msk[iB] = (unsigned char)(mB != 0);
            s_val[iB] = (unsigned char)((mB != 0) && tB >= 0);
            if (iB < NGATE) s_gc[iB] = 1.0 / (1.0 + exp(-eB));
        }
    }
    __syncthreads();

    if (tid < 64) {
        const int s = tid;
        const bool inS = s < MAX_SIZE;

        unsigned int valbit = 0, childbit = 0;
        #pragma unroll
        for (int d = 0; d < MAX_DEPTH - 1; ++d) {
            bool mn = inS && s_msk[(d + 1) * MAX_SIZE + s];
            unsigned long long bal = __ballot(mn);
            int nc = (int)__popcll(bal);
            if (nc < 1) nc = 1;
            bool val = inS && s_val[d * MAX_SIZE + s];
            if (val) valbit |= 1u << d;
            if (val && s < nc) childbit |= 1u << d;
        }

        double v7 = (inS && s_val[7 * MAX_SIZE + s]) ? 1.0 : 0.0;
        double e7 = inS ? s_e[7 * MAX_SIZE + s] : 0.0;
        double pw = waveSumD(e7 * v7);

        double cArr[MAX_DEPTH - 1];
        #pragma unroll
        for (int d = MAX_DEPTH - 2; d >= 0; --d) {
            double e  = inS ? s_e[d * MAX_SIZE + s] : 0.0;
            double gg = inS ? s_gc[d * MAX_SIZE + s] : 0.0;
            double cf = ((childbit >> d) & 1) ? gg : 0.0;
            double a  = fma(cf, pw, e);
            double ex = ((valbit >> d) & 1) ? exp(a) : 0.0;
            double s0 = ex, s1 = ex * cf, s2 = ex * e;
            waveSum3(s0, s1, s2);
            double inv = 1.0 / s0;
            double c   = s1 * inv;
            pw = fma(c, pw, s2 * inv);
            if (inS) s_coef[d * MAX_SIZE + s] = ex * inv;
            cArr[d] = c;
        }
        double prefix = 1.0;
        #pragma unroll
        for (int d = 0; d <= MAX_DEPTH - 2; ++d) {
            if (inS) s_coef[d * MAX_SIZE + s] *= prefix;
            prefix *= cArr[d];
        }
        if (inS) s_coef[7 * MAX_SIZE + s] = prefix * v7;
    }
    __syncthreads();

    {
        const int grp = tid >> 5;
        const int col = (tid & 31) << 2;
        double ax = 0.0, ay = 0.0, az = 0.0, aw = 0.0;
        #pragma unroll 1
        for (int jb = 0; jb < 40; jb += 5) {
            double wv[5];
            const float4* p[5];
            #pragma unroll
            for (int k = 0; k < 5; ++k) {
                int i = grp + (jb + k) * 8;
                wv[k] = s_coef[i];
                p[k] = (const float4*)(emb + (size_t)s_tok[i] * DIM + col);
            }
            float4 v[5];
            #pragma unroll
            for (int k = 0; k < 5; ++k) v[k] = *p[k];
            #pragma unroll
            for (int k = 0; k < 5; ++k) {
                ax += wv[k] * (double)v[k].x;
                ay += wv[k] * (double)v[k].y;
                az += wv[k] * (double)v[k].z;
                aw += wv[k] * (double)v[k].w;
            }
        }
        s_red[grp][col + 0] = ax;
        s_red[grp][col + 1] = ay;
        s_red[grp][col + 2] = az;
        s_red[grp][col + 3] = aw;
    }
    __syncthreads();
    if (tid < DIM) {
        double r = 0.0;
        #pragma unroll
        for (int g = 0; g < 8; ++g) r += s_red[g][tid];
        out[(size_t)tree * DIM + tid] = (float)r;
    }
}

extern "C" void kernel_launch(void* const* d_in, const int* in_sizes, int n_in,
                              void* d_out, int out_size, void* d_ws, size_t ws_size,
                              hipStream_t stream) {
    const int*   tokens = (const int*)d_in[0];
    const void*  masks  = d_in[1];
    const float* emb    = (const float*)d_in[2];
    const float* cw     = (const float*)d_in[3];
    float*       out    = (float*)d_out;

    // Workspace layout (8B alignment by construction):
    const size_t o_ts   = 0;
    const size_t o_pr   = o_ts + (size_t)VOCAB * 8;                    //  240 KB
    const size_t o_toff = o_pr + (size_t)NUM_TREES * TOT * 8;          // +51.2 MB
    const size_t need   = o_toff + (size_t)NUM_TREES * (NTILE + 1) * 4;// + 0.72 MB

    double* ts    = (double*)((char*)d_ws + o_ts);
    ull*    pairs = (ull*)((char*)d_ws + o_pr);
    int*    toff  = (int*)((char*)d_ws + o_toff);

    int ts_blocks = (VOCAB * 64 + 255) / 256;   // one wave per vocab row
    tokscore_kernel<<<ts_blocks, 256, 0, stream>>>(emb, cw, ts);

    if (ws_size >= need) {
        phaseA_kernel<<<NUM_TREES / TPA, 256, 0, stream>>>(tokens, masks, ts,
                                                           pairs, toff);
        for (int t = 0; t < NTILE; ++t)
            gather_tile_kernel<<<NUM_TREES / TPA, 256, 0, stream>>>(
                pairs, toff, emb, out, t);
    } else {
        encode_kernel<<<NUM_TREES, 256, 0, stream>>>(tokens, masks, emb, ts, out);
    }
}

// Round 6
// 393.356 us; speedup vs baseline: 1.0315x; 1.0315x over previous
//
#include <hip/hip_runtime.h>
#include <math.h>

#define NUM_TREES 20000
#define MAX_DEPTH 8
#define MAX_SIZE  40
#define VOCAB     30000
#define DIM       128
#define TOT       (MAX_DEPTH * MAX_SIZE)       // 320 tokens per tree
#define NGATE     ((MAX_DEPTH - 1) * MAX_SIZE) // 280 gated rows (depths 0..6)
#define NTILE     8
#define TILE_ROWS (VOCAB / NTILE)              // 3750 rows = 1.92 MB (L2-resident)
#define TPA       4                            // trees per block (wave per tree)

typedef unsigned long long ull;

__device__ __forceinline__ double waveSumD(double v) {
    v += __shfl_xor(v, 32);
    v += __shfl_xor(v, 16);
    v += __shfl_xor(v, 8);
    v += __shfl_xor(v, 4);
    v += __shfl_xor(v, 2);
    v += __shfl_xor(v, 1);
    return v;
}

// One packed butterfly for three independent fp64 sums (ILP hides the
// per-step shuffle latency across the three chains).
__device__ __forceinline__ void waveSum3(double& a, double& b, double& c) {
    #pragma unroll
    for (int m = 32; m >= 1; m >>= 1) {
        a += __shfl_xor(a, m);
        b += __shfl_xor(b, m);
        c += __shfl_xor(c, m);
    }
}

// masks may arrive as 1-byte bool or int32; probe word 0 (all-ones input:
// byte layout reads 0x01010101, int32 layout reads 0x00000001).
__device__ __forceinline__ int loadMask(const void* m, size_t idx, bool asByte) {
    return asByte ? (int)((const unsigned char*)m)[idx] : ((const int*)m)[idx];
}

// Phase 0: ts[v] = dot(embedding[v], context_weight) in fp64 (one wave per row)
__global__ __launch_bounds__(256) void tokscore_kernel(
        const float* __restrict__ emb, const float* __restrict__ cw,
        double* __restrict__ ts) {
    int row  = (blockIdx.x * blockDim.x + threadIdx.x) >> 6;
    int lane = threadIdx.x & 63;
    if (row >= VOCAB) return;
    float2 e2 = *(const float2*)(emb + (size_t)row * DIM + lane * 2);
    float2 w2 = *(const float2*)(cw + lane * 2);
    double p = (double)e2.x * (double)w2.x + (double)e2.y * (double)w2.y;
    p = waveSumD(p);
    if (lane == 0) ts[row] = p;
}

// Phase A: wave-per-tree fp64 recursion, register-only. Bucketing by vocab
// tile via ballot/popcount sweeps (no LDS, no atomics, no barriers).
// Emits packed pairs: coef-f32-bits in high 32, token in low 32.
__global__ __launch_bounds__(256, 6) void phaseA_kernel(
        const int* __restrict__ tokens, const void* __restrict__ masks,
        const double* __restrict__ ts,
        ull* __restrict__ pairs, int* __restrict__ toff) {
    const int tid  = threadIdx.x;
    const int w    = tid >> 6;          // wave id = local tree index
    const int s    = tid & 63;          // lane = sibling position
    const int tree = blockIdx.x * TPA + w;
    const size_t base = (size_t)tree * TOT;
    const bool mByte = (((const int*)masks)[0] != 1);   // see loadMask comment
    const bool inS = s < MAX_SIZE;

    // ---- per-wave load: tokens/masks/scores into registers.
    int    tok[MAX_DEPTH];
    double e[MAX_DEPTH];
    unsigned int valbit = 0, mskbit = 0;
    #pragma unroll
    for (int d = 0; d < MAX_DEPTH; ++d) {
        int t = -1, m = 0;
        if (inS) {
            t = tokens[base + d * MAX_SIZE + s];
            m = loadMask(masks, base + d * MAX_SIZE + s, mByte);
        }
        tok[d] = t < 0 ? 0 : t;
        e[d]   = inS ? ts[tok[d]] : 0.0;
        if (inS && m != 0) mskbit |= 1u << d;
        if (inS && m != 0 && t >= 0) valbit |= 1u << d;
    }
    unsigned int childbit = 0;
    #pragma unroll
    for (int d = 0; d < MAX_DEPTH - 1; ++d) {
        ull bal = __ballot((mskbit >> (d + 1)) & 1u);
        int nc = (int)__popcll(bal);
        if (nc < 1) nc = 1;
        if (((valbit >> d) & 1u) && s < nc) childbit |= 1u << d;
    }

    // ---- recursion (math identical to validated version; exp via HW f32
    // exp: rel err ~1e-7, cancels in the softmax ratio).
    double v7 = ((valbit >> 7) & 1u) ? 1.0 : 0.0;
    double pw = waveSumD(e[7] * v7);

    float  attnf[MAX_DEPTH - 1];
    double cArr[MAX_DEPTH - 1];
    #pragma unroll
    for (int d = MAX_DEPTH - 2; d >= 0; --d) {
        float  gf = 1.0f / (1.0f + __expf((float)(-e[d])));
        double cf = ((childbit >> d) & 1u) ? (double)gf : 0.0;  // gate*child
        double a  = fma(cf, pw, e[d]);
        double ex = ((valbit >> d) & 1u) ? (double)__expf((float)a) : 0.0;
        double s0 = ex;            // -> den
        double s1 = ex * cf;       // -> c * den
        double s2 = ex * e[d];     // -> (sum attn*e) * den
        waveSum3(s0, s1, s2);
        double inv = 1.0 / s0;
        double c   = s1 * inv;
        pw = fma(c, pw, s2 * inv);
        attnf[d] = (float)(ex * inv);   // attn
        cArr[d]  = c;
    }
    float coef[MAX_DEPTH];
    double prefix = 1.0;
    #pragma unroll
    for (int d = 0; d <= MAX_DEPTH - 2; ++d) {
        coef[d] = (float)(prefix * (double)attnf[d]);
        prefix *= cArr[d];
    }
    coef[MAX_DEPTH - 1] = (float)(prefix * v7);

    // ---- ballot-based tile bucketing (all indices compile-time after
    // unroll -> stays in registers).
    int tl[MAX_DEPTH];
    unsigned int nzbit = 0;
    #pragma unroll
    for (int d = 0; d < MAX_DEPTH; ++d) {
        tl[d] = tok[d] / TILE_ROWS;
        if (coef[d] != 0.0f) nzbit |= 1u << d;
    }
    const ull ltm = (1ull << s) - 1ull;    // lanes below me

    int cnt[NTILE];
    #pragma unroll
    for (int t = 0; t < NTILE; ++t) cnt[t] = 0;
    #pragma unroll
    for (int d = 0; d < MAX_DEPTH; ++d) {
        bool nz = (nzbit >> d) & 1u;
        #pragma unroll
        for (int t = 0; t < NTILE; ++t)
            cnt[t] += (int)__popcll(__ballot(nz && tl[d] == t));
    }
    int hoff[NTILE + 1];
    hoff[0] = 0;
    #pragma unroll
    for (int t = 0; t < NTILE; ++t) hoff[t + 1] = hoff[t] + cnt[t];

    int ridx[NTILE];
    #pragma unroll
    for (int t = 0; t < NTILE; ++t) ridx[t] = hoff[t];
    #pragma unroll
    for (int d = 0; d < MAX_DEPTH; ++d) {
        bool nz = (nzbit >> d) & 1u;
        int slot = -1;
        #pragma unroll
        for (int t = 0; t < NTILE; ++t) {
            ull m = __ballot(nz && tl[d] == t);
            if (nz && tl[d] == t) slot = ridx[t] + (int)__popcll(m & ltm);
            ridx[t] += (int)__popcll(m);
        }
        if (slot >= 0)
            pairs[base + slot] =
                ((ull)__float_as_uint(coef[d]) << 32) | (ull)(unsigned)tok[d];
    }
    // toff write: select hoff[s] without dynamic indexing (cndmask chain).
    int hv = 0;
    #pragma unroll
    for (int t = 1; t <= NTILE; ++t) hv = (s == t) ? hoff[t] : hv;
    if (s <= NTILE) toff[tree * (NTILE + 1) + s] = (int)base + hv;
}

// Phase B: per-tile gather, wave-per-tree, fp32. Pair segment is staged to
// LDS once (coalesced), then read via uniform-address ds_read_b128
// (broadcast, short latency, off the global-load queue). Half-wave trick:
// lanes 0-31 process even rows, lanes 32-63 odd rows, each lane a float4
// column slice -> one global_load_dwordx4 covers TWO rows (1KB/instr).
// out itself is the fp32 accumulator: tile 0 init, tiles 1..7 RMW.
__global__ __launch_bounds__(256, 8) void gather_tile_kernel(
        const ull* __restrict__ pairs, const int* __restrict__ toff,
        const float* __restrict__ emb, float* __restrict__ out, int tile) {
    __shared__ ull l_pair[TPA][TOT];   // 10 KB

    const int tid  = threadIdx.x;
    const int w    = tid >> 6;
    const int lane = tid & 63;
    const int tree = blockIdx.x * TPA + w;

    int beg = __builtin_amdgcn_readfirstlane(toff[tree * (NTILE + 1) + tile]);
    int end = __builtin_amdgcn_readfirstlane(toff[tree * (NTILE + 1) + tile + 1]);
    const int n = end - beg;

    // Stage (coalesced 512B per iter). Wave-local: same wave writes & reads,
    // compiler's lgkmcnt ordering suffices; no barrier.
    for (int i = lane; i < n; i += 64) l_pair[w][i] = pairs[beg + i];

    const bool hi = lane >= 32;            // 0: even row of pair, 1: odd row
    const int  cb = (lane & 31) << 2;      // column base (floats)
    float a0 = 0.0f, a1 = 0.0f, a2 = 0.0f, a3 = 0.0f;

    int j = 0;
    for (; j + 8 <= n; j += 8) {           // 8 rows = 4 dwordx4 loads in flight
        uint4 q0 = *(const uint4*)&l_pair[w][j + 0];
        uint4 q1 = *(const uint4*)&l_pair[w][j + 2];
        uint4 q2 = *(const uint4*)&l_pair[w][j + 4];
        uint4 q3 = *(const uint4*)&l_pair[w][j + 6];
        unsigned tk0 = hi ? q0.z : q0.x;  float w0 = __uint_as_float(hi ? q0.w : q0.y);
        unsigned tk1 = hi ? q1.z : q1.x;  float w1 = __uint_as_float(hi ? q1.w : q1.y);
        unsigned tk2 = hi ? q2.z : q2.x;  float w2 = __uint_as_float(hi ? q2.w : q2.y);
        unsigned tk3 = hi ? q3.z : q3.x;  float w3 = __uint_as_float(hi ? q3.w : q3.y);
        const float4 v0 = *(const float4*)(emb + (size_t)tk0 * DIM + cb);
        const float4 v1 = *(const float4*)(emb + (size_t)tk1 * DIM + cb);
        const float4 v2 = *(const float4*)(emb + (size_t)tk2 * DIM + cb);
        const float4 v3 = *(const float4*)(emb + (size_t)tk3 * DIM + cb);
        a0 = fmaf(w0, v0.x, a0); a1 = fmaf(w0, v0.y, a1);
        a2 = fmaf(w0, v0.z, a2); a3 = fmaf(w0, v0.w, a3);
        a0 = fmaf(w1, v1.x, a0); a1 = fmaf(w1, v1.y, a1);
        a2 = fmaf(w1, v1.z, a2); a3 = fmaf(w1, v1.w, a3);
        a0 = fmaf(w2, v2.x, a0); a1 = fmaf(w2, v2.y, a1);
        a2 = fmaf(w2, v2.z, a2); a3 = fmaf(w2, v2.w, a3);
        a0 = fmaf(w3, v3.x, a0); a1 = fmaf(w3, v3.y, a1);
        a2 = fmaf(w3, v3.z, a2); a3 = fmaf(w3, v3.w, a3);
    }
    for (; j + 2 <= n; j += 2) {
        uint4 q = *(const uint4*)&l_pair[w][j];
        unsigned tk = hi ? q.z : q.x;
        float    wt = __uint_as_float(hi ? q.w : q.y);
        const float4 v = *(const float4*)(emb + (size_t)tk * DIM + cb);
        a0 = fmaf(wt, v.x, a0); a1 = fmaf(wt, v.y, a1);
        a2 = fmaf(wt, v.z, a2); a3 = fmaf(wt, v.w, a3);
    }
    if (j < n) {                            // single leftover row: upper half
        ull pr = l_pair[w][j];              // contributes 0
        unsigned tk = (unsigned)pr;
        float    wt = hi ? 0.0f : __uint_as_float((unsigned)(pr >> 32));
        const float4 v = *(const float4*)(emb + (size_t)tk * DIM + cb);
        a0 = fmaf(wt, v.x, a0); a1 = fmaf(wt, v.y, a1);
        a2 = fmaf(wt, v.z, a2); a3 = fmaf(wt, v.w, a3);
    }

    // Combine half-waves (lane i and i+32 hold same columns).
    a0 += __shfl_xor(a0, 32);
    a1 += __shfl_xor(a1, 32);
    a2 += __shfl_xor(a2, 32);
    a3 += __shfl_xor(a3, 32);

    if (lane < 32) {
        float* op = out + (size_t)tree * DIM + cb;
        if (tile == 0) {
            *(float4*)op = make_float4(a0, a1, a2, a3);
        } else {
            float4 p = *(const float4*)op;
            *(float4*)op = make_float4(p.x + a0, p.y + a1, p.z + a2, p.w + a3);
        }
    }
}

// ---- Fallback single-kernel path (validated round 1) for small workspaces.
__global__ __launch_bounds__(256, 8) void encode_kernel(
        const int* __restrict__ tokens, const void* __restrict__ masks,
        const float* __restrict__ emb, const double* __restrict__ ts,
        float* __restrict__ out) {
    __shared__ int           s_tok[TOT];
    __shared__ double        s_e[TOT];
    __shared__ double        s_gc[NGATE];
    __shared__ unsigned char s_val[TOT];
    __shared__ unsigned char s_msk[TOT];
    __shared__ double        s_coef[TOT];
    __shared__ double        s_red[8][DIM];

    const int tree = blockIdx.x;
    const int tid  = threadIdx.x;
    const size_t base = (size_t)tree * TOT;
    const bool mByte = (((const int*)masks)[0] != 1);

    {
        const int iA = tid, iB = tid + 256;
        int tA = tokens[base + iA];
        int mA = loadMask(masks, base + iA, mByte);
        int tB = 0, mB = 0;
        if (iB < TOT) {
            tB = tokens[base + iB];
            mB = loadMask(masks, base + iB, mByte);
        }
        int tcA = tA < 0 ? 0 : tA;
        double eA = ts[tcA];
        s_tok[iA] = tcA;
        s_e[iA]   = eA;
        s_msk[iA] = (unsigned char)(mA != 0);
        s_val[iA] = (unsigned char)((mA != 0) && tA >= 0);
        if (iA < NGATE) s_gc[iA] = 1.0 / (1.0 + exp(-eA));
        if (iB < TOT) {
            int tcB = tB < 0 ? 0 : tB;
            double eB = ts[tcB];
            s_tok[iB] = tcB;
            s_e[iB]   = eB;
            s_msk[iB] = (unsigned char)(mB != 0);
            s_val[iB] = (unsigned char)((mB != 0) && tB >= 0);
            if (iB < NGATE) s_gc[iB] = 1.0 / (1.0 + exp(-eB));
        }
    }
    __syncthreads();

    if (tid < 64) {
        const int s = tid;
        const bool inS = s < MAX_SIZE;

        unsigned int valbit = 0, childbit = 0;
        #pragma unroll
        for (int d = 0; d < MAX_DEPTH - 1; ++d) {
            bool mn = inS && s_msk[(d + 1) * MAX_SIZE + s];
            unsigned long long bal = __ballot(mn);
            int nc = (int)__popcll(bal);
            if (nc < 1) nc = 1;
            bool val = inS && s_val[d * MAX_SIZE + s];
            if (val) valbit |= 1u << d;
            if (val && s < nc) childbit |= 1u << d;
        }

        double v7 = (inS && s_val[7 * MAX_SIZE + s]) ? 1.0 : 0.0;
        double e7 = inS ? s_e[7 * MAX_SIZE + s] : 0.0;
        double pw = waveSumD(e7 * v7);

        double cArr[MAX_DEPTH - 1];
        #pragma unroll
        for (int d = MAX_DEPTH - 2; d >= 0; --d) {
            double e  = inS ? s_e[d * MAX_SIZE + s] : 0.0;
            double gg = inS ? s_gc[d * MAX_SIZE + s] : 0.0;
            double cf = ((childbit >> d) & 1) ? gg : 0.0;
            double a  = fma(cf, pw, e);
            double ex = ((valbit >> d) & 1) ? exp(a) : 0.0;
            double s0 = ex, s1 = ex * cf, s2 = ex * e;
            waveSum3(s0, s1, s2);
            double inv = 1.0 / s0;
            double c   = s1 * inv;
            pw = fma(c, pw, s2 * inv);
            if (inS) s_coef[d * MAX_SIZE + s] = ex * inv;
            cArr[d] = c;
        }
        double prefix = 1.0;
        #pragma unroll
        for (int d = 0; d <= MAX_DEPTH - 2; ++d) {
            if (inS) s_coef[d * MAX_SIZE + s] *= prefix;
            prefix *= cArr[d];
        }
        if (inS) s_coef[7 * MAX_SIZE + s] = prefix * v7;
    }
    __syncthreads();

    {
        const int grp = tid >> 5;
        const int col = (tid & 31) << 2;
        double ax = 0.0, ay = 0.0, az = 0.0, aw = 0.0;
        #pragma unroll 1
        for (int jb = 0; jb < 40; jb += 5) {
            double wv[5];
            const float4* p[5];
            #pragma unroll
            for (int k = 0; k < 5; ++k) {
                int i = grp + (jb + k) * 8;
                wv[k] = s_coef[i];
                p[k] = (const float4*)(emb + (size_t)s_tok[i] * DIM + col);
            }
            float4 v[5];
            #pragma unroll
            for (int k = 0; k < 5; ++k) v[k] = *p[k];
            #pragma unroll
            for (int k = 0; k < 5; ++k) {
                ax += wv[k] * (double)v[k].x;
                ay += wv[k] * (double)v[k].y;
                az += wv[k] * (double)v[k].z;
                aw += wv[k] * (double)v[k].w;
            }
        }
        s_red[grp][col + 0] = ax;
        s_red[grp][col + 1] = ay;
        s_red[grp][col + 2] = az;
        s_red[grp][col + 3] = aw;
    }
    __syncthreads();
    if (tid < DIM) {
        double r = 0.0;
        #pragma unroll
        for (int g = 0; g < 8; ++g) r += s_red[g][tid];
        out[(size_t)tree * DIM + tid] = (float)r;
    }
}

extern "C" void kernel_launch(void* const* d_in, const int* in_sizes, int n_in,
                              void* d_out, int out_size, void* d_ws, size_t ws_size,
                              hipStream_t stream) {
    const int*   tokens = (const int*)d_in[0];
    const void*  masks  = d_in[1];
    const float* emb    = (const float*)d_in[2];
    const float* cw     = (const float*)d_in[3];
    float*       out    = (float*)d_out;

    // Workspace layout (8B alignment by construction):
    const size_t o_ts   = 0;
    const size_t o_pr   = o_ts + (size_t)VOCAB * 8;                    //  240 KB
    const size_t o_toff = o_pr + (size_t)NUM_TREES * TOT * 8;          // +51.2 MB
    const size_t need   = o_toff + (size_t)NUM_TREES * (NTILE + 1) * 4;// + 0.72 MB

    double* ts    = (double*)((char*)d_ws + o_ts);
    ull*    pairs = (ull*)((char*)d_ws + o_pr);
    int*    toff  = (int*)((char*)d_ws + o_toff);

    int ts_blocks = (VOCAB * 64 + 255) / 256;   // one wave per vocab row
    tokscore_kernel<<<ts_blocks, 256, 0, stream>>>(emb, cw, ts);

    if (ws_size >= need) {
        phaseA_kernel<<<NUM_TREES / TPA, 256, 0, stream>>>(tokens, masks, ts,
                                                           pairs, toff);
        for (int t = 0; t < NTILE; ++t)
            gather_tile_kernel<<<NUM_TREES / TPA, 256, 0, stream>>>(
                pairs, toff, emb, out, t);
    } else {
        encode_kernel<<<NUM_TREES, 256, 0, stream>>>(tokens, masks, emb, ts, out);
    }
}